// Round 1
// baseline (9282.478 us; speedup 1.0000x reference)
//
#include <hip/hip_runtime.h>
#include <math.h>

#define NB 16       // batch
#define NE 256      // embed dim
#define NH 256      // hidden dim
#define NLV 12      // levels
#define NN 4095     // nodes = 2^12 - 1
#define OUTW 512    // output last-dim (2H)

#define SEG_ZERO 0
#define SEG_EMB 1     // base=emb table; row = ids[b*NN + s + m]
#define SEG_CHILD 2   // base + (b*NN + 2*(s+m)+1)*NH  (512 contiguous floats = both children)
#define SEG_LVL 3     // base + gr*NH
#define SEG_PARENT 4  // base + (b*(M/2) + m/2)*NH

__device__ __forceinline__ float sigf(float x){ return 1.0f/(1.0f + expf(-x)); }

__device__ __forceinline__ const float* seg_row_ptr(int mode, const float* base, const int* ids,
                                                    int b, int m, int s, int logM, int segK){
  switch(mode){
    case SEG_EMB:    return base + (size_t)ids[b*NN + s + m] * segK;
    case SEG_CHILD:  return base + ((size_t)(b*NN + 2*(s+m) + 1)) * NH;
    case SEG_LVL:    return base + (((size_t)b << logM) + m) * NH;
    case SEG_PARENT: return base + ((size_t)(b*(1<<(logM-1)) + (m>>1))) * NH;
    default:         return nullptr;
  }
}

// Generic fp32 GEMM: G[lr, :] = sum_seg A_seg[row] @ W + bias
// A is a virtual concatenation of up to 3 row-segments resolved per row.
// 64x64 tile per 256-thread block, 4x4 per-thread microtile, K-tile 16.
__global__ __launch_bounds__(256) void gemm_f32(
    int R, int r0, int Ncols, int logM, int s,
    const int* __restrict__ ids,
    int mode0, const float* __restrict__ b0, int k0,
    int mode1, const float* __restrict__ b1, int k1,
    int mode2, const float* __restrict__ b2, int k2,
    const float* __restrict__ W, const float* __restrict__ bias,
    float* __restrict__ G)
{
  __shared__ float As[16][64];
  __shared__ float Bs[16][64];
  int t = threadIdx.x;
  int row = t & 63;        // loader row (A) / col (W)
  int kq  = t >> 6;        // which 4-k group this thread loads
  int lr = blockIdx.x*64 + row;   // local (chunk) row
  int gr = r0 + lr;               // global row in level
  int M = 1 << logM;
  int b = gr >> logM, m = gr & (M-1);
  const float* rp0 = nullptr; const float* rp1 = nullptr; const float* rp2 = nullptr;
  if (gr < R){
    rp0 = seg_row_ptr(mode0, b0, ids, b, m, s, logM, k0);
    rp1 = seg_row_ptr(mode1, b1, ids, b, m, s, logM, k1);
    rp2 = seg_row_ptr(mode2, b2, ids, b, m, s, logM, k2);
  }
  int kTot = k0 + k1 + k2;
  int cb = blockIdx.y * 64;
  int tr4 = (t & 15)*4, tc4 = (t >> 4)*4;
  float acc[4][4] = {};
  for (int kt = 0; kt < kTot; kt += 16){
    int kk = kt + kq*4;
    const float* rp; int kl;
    if (kk < k0){ rp = rp0; kl = kk; }
    else if (kk < k0 + k1){ rp = rp1; kl = kk - k0; }
    else { rp = rp2; kl = kk - k0 - k1; }
    float4 av = make_float4(0.f,0.f,0.f,0.f);
    if (rp) av = *reinterpret_cast<const float4*>(rp + kl);
    const float* wp = W + (size_t)(kt + kq*4)*Ncols + cb + row;
    float w0 = wp[0];
    float w1 = wp[(size_t)Ncols];
    float w2 = wp[2*(size_t)Ncols];
    float w3 = wp[3*(size_t)Ncols];
    __syncthreads();
    As[kq*4+0][row] = av.x; As[kq*4+1][row] = av.y;
    As[kq*4+2][row] = av.z; As[kq*4+3][row] = av.w;
    Bs[kq*4+0][row] = w0; Bs[kq*4+1][row] = w1;
    Bs[kq*4+2][row] = w2; Bs[kq*4+3][row] = w3;
    __syncthreads();
    #pragma unroll
    for (int k = 0; k < 16; ++k){
      float4 a = *reinterpret_cast<const float4*>(&As[k][tr4]);
      float4 w = *reinterpret_cast<const float4*>(&Bs[k][tc4]);
      acc[0][0] += a.x*w.x; acc[0][1] += a.x*w.y; acc[0][2] += a.x*w.z; acc[0][3] += a.x*w.w;
      acc[1][0] += a.y*w.x; acc[1][1] += a.y*w.y; acc[1][2] += a.y*w.z; acc[1][3] += a.y*w.w;
      acc[2][0] += a.z*w.x; acc[2][1] += a.z*w.y; acc[2][2] += a.z*w.z; acc[2][3] += a.z*w.w;
      acc[3][0] += a.w*w.x; acc[3][1] += a.w*w.y; acc[3][2] += a.w*w.z; acc[3][3] += a.w*w.w;
    }
  }
  float4 bv = *reinterpret_cast<const float4*>(&bias[cb + tc4]);
  #pragma unroll
  for (int i = 0; i < 4; ++i){
    int lrr = blockIdx.x*64 + tr4 + i;
    int grr = r0 + lrr;
    if (grr < R){
      float* gp = G + (size_t)lrr*Ncols + cb + tc4;
      gp[0] = acc[i][0] + bv.x; gp[1] = acc[i][1] + bv.y;
      gp[2] = acc[i][2] + bv.z; gp[3] = acc[i][3] + bv.w;
    }
  }
}

// BU node epilogue: G cols = [i(256)|o(256)|u(256)|f0(256)|f1(256)]  (width 1280)
__global__ void epi_bu_node(int R, int r0, int logM, int s,
    const float* __restrict__ G, const float* __restrict__ cce,
    float* __restrict__ c_lvl, float* __restrict__ h_lvl, float* __restrict__ out)
{
  int lr = blockIdx.x, gr = r0 + lr;
  if (gr >= R) return;
  int hh = threadIdx.x;
  const float* g = G + (size_t)lr*1280;
  float iv = sigf(g[hh]);
  float ov = sigf(g[256+hh]);
  float uv = tanhf(g[512+hh]);
  float f0 = sigf(g[768+hh]);
  float f1 = sigf(g[1024+hh]);
  int M = 1<<logM; int b = gr >> logM, m = gr & (M-1);
  int j = s + m;
  float c0 = 0.f, c1 = 0.f;
  if (cce){
    c0 = cce[((size_t)(b*NN + 2*j+1))*NH + hh];
    c1 = cce[((size_t)(b*NN + 2*j+2))*NH + hh];
  }
  float c = iv*uv + f0*c0 + f1*c1;
  float h = ov * tanhf(c);
  c_lvl[(size_t)gr*NH + hh] = c;
  h_lvl[(size_t)gr*NH + hh] = h;
  out[((size_t)(b*NN + j))*OUTW + hh] = h;
}

// TD node epilogue: G cols = [i|o|u|f0|f1|fpar] (width 1536)
__global__ void epi_td_node(int R, int r0, int logM, int s,
    const float* __restrict__ G, const float* __restrict__ cce, const float* __restrict__ pc,
    float* __restrict__ c_lvl, float* __restrict__ h_lvl, float* __restrict__ out)
{
  int lr = blockIdx.x, gr = r0 + lr;
  if (gr >= R) return;
  int hh = threadIdx.x;
  const float* g = G + (size_t)lr*1536;
  float iv = sigf(g[hh]);
  float ov = sigf(g[256+hh]);
  float uv = tanhf(g[512+hh]);
  float f0 = sigf(g[768+hh]);
  float f1 = sigf(g[1024+hh]);
  float fp = sigf(g[1280+hh]);
  int M = 1<<logM; int b = gr >> logM, m = gr & (M-1);
  int j = s + m;
  float c0 = 0.f, c1 = 0.f;
  if (cce){
    c0 = cce[((size_t)(b*NN + 2*j+1))*NH + hh];
    c1 = cce[((size_t)(b*NN + 2*j+2))*NH + hh];
  }
  float pcv = pc[(size_t)gr*NH + hh];
  float c = iv*uv + f0*c0 + f1*c1 + fp*pcv;
  float h = ov * tanhf(c);
  c_lvl[(size_t)gr*NH + hh] = c;
  h_lvl[(size_t)gr*NH + hh] = h;
  out[((size_t)(b*NN + j))*OUTW + 256 + hh] = h;
}

// Edge-LSTM epilogue: G cols = [i|f|g|o] (width 1024)
// parentMode: c_prev indexed by parent row. dstLevelMode: write to global node slot.
__global__ void epi_lstm(int R, int r0, int logM, int s,
    const float* __restrict__ G, const float* __restrict__ cprev, int parentMode,
    float* __restrict__ dst_h, float* __restrict__ dst_c, int dstLevelMode)
{
  int lr = blockIdx.x, gr = r0 + lr;
  if (gr >= R) return;
  int hh = threadIdx.x;
  const float* g = G + (size_t)lr*1024;
  float iv = sigf(g[hh]);
  float fv = sigf(g[256+hh]);
  float gg = tanhf(g[512+hh]);
  float ov = sigf(g[768+hh]);
  int M = 1<<logM; int b = gr >> logM, m = gr & (M-1);
  float cp;
  if (parentMode) cp = cprev[((size_t)(b*(M>>1) + (m>>1)))*NH + hh];
  else            cp = cprev[(size_t)gr*NH + hh];
  float c2 = fv*cp + iv*gg;
  float h2 = ov*tanhf(c2);
  size_t di;
  if (dstLevelMode) di = ((size_t)(b*NN + s + m))*NH + hh;
  else              di = (size_t)gr*NH + hh;
  dst_h[di] = h2; dst_c[di] = c2;
}

// ---- weight packing (runs every call; ~14 MB total) ----

// BU node combined: K=768 rows = [x(256)|cat(512)], 1280 cols = [iou(768)|f0(256)|f1(256)]
__global__ void pack_bu_node(const float* __restrict__ Wioux, const float* __restrict__ Wiouh,
                             const float* __restrict__ Wfx, const float* __restrict__ Wfh,
                             const float* __restrict__ bioux, const float* __restrict__ bfx,
                             float* __restrict__ Wd, float* __restrict__ bd)
{
  int tid = blockIdx.x*256 + threadIdx.x;
  if (tid < 768*1280){
    int k = tid / 1280, n = tid % 1280;
    float v;
    if (n < 768){
      v = (k < 256) ? Wioux[k*768 + n] : Wiouh[(k-256)*768 + n];
    } else {
      int kidx = (n < 1024) ? 0 : 1;
      int nn = n - 768 - kidx*256;
      v = (k < 256) ? Wfx[k*256 + nn] : Wfh[((size_t)kidx*512 + (k-256))*256 + nn];
    }
    Wd[tid] = v;
  }
  if (tid < 1280) bd[tid] = (tid < 768) ? bioux[tid] : bfx[(tid-768) & 255];
}

// Edge-LSTM combined: K=512 rows = [x(256)|h(256)], 1024 cols; bias = bih + bhh
__global__ void pack_edge(const float* __restrict__ Wih, const float* __restrict__ Whh,
                          const float* __restrict__ bih, const float* __restrict__ bhh,
                          float* __restrict__ Wd, float* __restrict__ bd)
{
  int tid = blockIdx.x*256 + threadIdx.x;
  if (tid < 512*1024){
    int k = tid / 1024, n = tid % 1024;
    Wd[tid] = (k < 256) ? Wih[k*1024 + n] : Whh[(k-256)*1024 + n];
  }
  if (tid < 1024) bd[tid] = bih[tid] + bhh[tid];
}

// TD node combined: K=1024 rows = [x(256)|cat(512)|ph(256)],
// 1536 cols = [iou(768)|f_ch0(256)|f_ch1(256)|f_par(256)]
// Note: pcat = [ph, cat] in the reference, so Wfchild/Wfparent rows 0..255 are ph,
// rows 256..767 are cat. Our combined k: cat=[256,768) -> pcat row k; ph=[768,1024) -> pcat row k-768.
__global__ void pack_td_node(const float* __restrict__ Wioux, const float* __restrict__ Wiouhc,
                             const float* __restrict__ Wiouhp, const float* __restrict__ Wfx,
                             const float* __restrict__ Wfchild, const float* __restrict__ Wfparent,
                             const float* __restrict__ bioux, const float* __restrict__ bfx,
                             float* __restrict__ Wd, float* __restrict__ bd)
{
  int tid = blockIdx.x*256 + threadIdx.x;
  if (tid < 1024*1536){
    int k = tid / 1536, n = tid % 1536;
    float v;
    if (n < 768){
      v = (k < 256) ? Wioux[k*768 + n]
        : (k < 768) ? Wiouhc[(k-256)*768 + n]
                    : Wiouhp[(k-768)*768 + n];
    } else if (n < 1280){
      int kidx = (n < 1024) ? 0 : 1;
      int nn = n - 768 - kidx*256;
      v = (k < 256) ? Wfx[k*256 + nn]
        : (k < 768) ? Wfchild[((size_t)kidx*768 + k)*256 + nn]
                    : Wfchild[((size_t)kidx*768 + (k-768))*256 + nn];
    } else {
      int nn = n - 1280;
      v = (k < 256) ? Wfx[k*256 + nn]
        : (k < 768) ? Wfparent[(size_t)k*256 + nn]
                    : Wfparent[(size_t)(k-768)*256 + nn];
    }
    Wd[tid] = v;
  }
  if (tid < 1536) bd[tid] = (tid < 768) ? bioux[tid] : bfx[(tid-768) & 255];
}

static inline int imin(int a, int b){ return a < b ? a : b; }

extern "C" void kernel_launch(void* const* d_in, const int* in_sizes, int n_in,
                              void* d_out, int out_size, void* d_ws, size_t ws_size,
                              hipStream_t stream)
{
  const float* node_emb  = (const float*)d_in[0];
  const float* edge_emb  = (const float*)d_in[1];
  const float* bu_Wioux  = (const float*)d_in[2];
  const float* bu_bioux  = (const float*)d_in[3];
  const float* bu_Wfx    = (const float*)d_in[4];
  const float* bu_bfx    = (const float*)d_in[5];
  const float* bu_Wiouh  = (const float*)d_in[6];
  const float* bu_Wfh    = (const float*)d_in[7];
  const float* bu_eWih   = (const float*)d_in[8];
  const float* bu_eWhh   = (const float*)d_in[9];
  const float* bu_ebih   = (const float*)d_in[10];
  const float* bu_ebhh   = (const float*)d_in[11];
  const float* td_Wioux  = (const float*)d_in[12];
  const float* td_bioux  = (const float*)d_in[13];
  const float* td_Wfx    = (const float*)d_in[14];
  const float* td_bfx    = (const float*)d_in[15];
  const float* td_Wiouhc = (const float*)d_in[16];
  const float* td_Wiouhp = (const float*)d_in[17];
  const float* td_Wfchild= (const float*)d_in[18];
  const float* td_Wfparent=(const float*)d_in[19];
  const float* td_eWih   = (const float*)d_in[20];
  const float* td_eWhh   = (const float*)d_in[21];
  const float* td_ebih   = (const float*)d_in[22];
  const float* td_ebhh   = (const float*)d_in[23];
  const int* node_ids    = (const int*)d_in[24];
  const int* edge_ids    = (const int*)d_in[25];
  float* out = (float*)d_out;

  float* w = (float*)d_ws;
  size_t off = 0;
  float* Wbun = w + off; off += (size_t)768*1280;
  float* Wbue = w + off; off += (size_t)512*1024;
  float* Wtdn = w + off; off += (size_t)1024*1536;
  float* Wtde = w + off; off += (size_t)512*1024;
  float* bbun = w + off; off += 1280;
  float* bbue = w + off; off += 1024;
  float* btdn = w + off; off += 1536;
  float* btde = w + off; off += 1024;
  float* he_all = w + off; off += (size_t)NB*NN*NH;
  float* ce_all = w + off; off += (size_t)NB*NN*NH;
  float* c_lvl  = w + off; off += (size_t)NB*2048*NH;
  float* h_lvl  = w + off; off += (size_t)NB*2048*NH;
  float* ph     = w + off; off += (size_t)NB*2048*NH;
  float* pc     = w + off; off += (size_t)NB*2048*NH;
  float* G      = w + off;

  size_t totalF = ws_size / 4;
  int CHUNK = 64;
  if (totalF > off){
    size_t remain = totalF - off;
    size_t c = (remain / 1536) & ~(size_t)63;
    if (c > 8192) c = 8192;
    if (c >= 64) CHUNK = (int)c;
  }

  pack_bu_node<<<(768*1280+255)/256, 256, 0, stream>>>(bu_Wioux, bu_Wiouh, bu_Wfx, bu_Wfh, bu_bioux, bu_bfx, Wbun, bbun);
  pack_edge   <<<(512*1024+255)/256, 256, 0, stream>>>(bu_eWih, bu_eWhh, bu_ebih, bu_ebhh, Wbue, bbue);
  pack_td_node<<<(1024*1536+255)/256, 256, 0, stream>>>(td_Wioux, td_Wiouhc, td_Wiouhp, td_Wfx, td_Wfchild, td_Wfparent, td_bioux, td_bfx, Wtdn, btdn);
  pack_edge   <<<(512*1024+255)/256, 256, 0, stream>>>(td_eWih, td_eWhh, td_ebih, td_ebhh, Wtde, btde);

  // ---------- bottom-up ----------
  for (int l = NLV-1; l >= 0; --l){
    int M = 1<<l, s = M-1, R = NB*M;
    bool leaf = (l == NLV-1);
    for (int r0 = 0; r0 < R; r0 += CHUNK){
      int cr = imin(CHUNK, R - r0);
      dim3 g1((cr+63)/64, 1280/64);
      gemm_f32<<<g1, 256, 0, stream>>>(R, r0, 1280, l, s, node_ids,
          SEG_EMB, node_emb, 256,
          leaf ? SEG_ZERO : SEG_CHILD, leaf ? nullptr : he_all, 512,
          SEG_ZERO, nullptr, 0,
          Wbun, bbun, G);
      epi_bu_node<<<cr, 256, 0, stream>>>(R, r0, l, s, G, leaf ? nullptr : ce_all, c_lvl, h_lvl, out);
    }
    for (int r0 = 0; r0 < R; r0 += CHUNK){
      int cr = imin(CHUNK, R - r0);
      dim3 g2((cr+63)/64, 1024/64);
      gemm_f32<<<g2, 256, 0, stream>>>(R, r0, 1024, l, s, edge_ids,
          SEG_EMB, edge_emb, 256,
          SEG_LVL, h_lvl, 256,
          SEG_ZERO, nullptr, 0,
          Wbue, bbue, G);
      epi_lstm<<<cr, 256, 0, stream>>>(R, r0, l, s, G, c_lvl, 0, he_all, ce_all, 1);
    }
  }

  // ---------- top-down ----------
  hipMemsetAsync(ph, 0, (size_t)NB*NH*sizeof(float), stream);
  hipMemsetAsync(pc, 0, (size_t)NB*NH*sizeof(float), stream);
  for (int l = 0; l < NLV; ++l){
    int M = 1<<l, s = M-1, R = NB*M;
    bool leaf = (l == NLV-1);
    for (int r0 = 0; r0 < R; r0 += CHUNK){
      int cr = imin(CHUNK, R - r0);
      dim3 g1((cr+63)/64, 1536/64);
      gemm_f32<<<g1, 256, 0, stream>>>(R, r0, 1536, l, s, node_ids,
          SEG_EMB, node_emb, 256,
          leaf ? SEG_ZERO : SEG_CHILD, leaf ? nullptr : he_all, 512,
          SEG_LVL, ph, 256,
          Wtdn, btdn, G);
      epi_td_node<<<cr, 256, 0, stream>>>(R, r0, l, s, G, leaf ? nullptr : ce_all, pc, c_lvl, h_lvl, out);
    }
    if (!leaf){
      int M2 = 2*M, s2 = 2*M-1, R2 = NB*M2;
      for (int r0 = 0; r0 < R2; r0 += CHUNK){
        int cr = imin(CHUNK, R2 - r0);
        dim3 g2((cr+63)/64, 1024/64);
        gemm_f32<<<g2, 256, 0, stream>>>(R2, r0, 1024, l+1, s2, edge_ids,
            SEG_EMB, edge_emb, 256,
            SEG_PARENT, h_lvl, 256,
            SEG_ZERO, nullptr, 0,
            Wtde, btde, G);
        epi_lstm<<<cr, 256, 0, stream>>>(R2, r0, l+1, s2, G, c_lvl, 1, ph, pc, 0);
      }
    }
  }
}

// Round 2
// 5039.299 us; speedup vs baseline: 1.8420x; 1.8420x over previous
//
#include <hip/hip_runtime.h>
#include <math.h>

#define NB 16       // batch
#define NE 256      // embed dim
#define NH 256      // hidden dim
#define NLV 12      // levels
#define NN 4095     // nodes = 2^12 - 1
#define OUTW 512    // output last-dim (2H)

#define SEG_ZERO 0
#define SEG_EMB 1     // row = ids[b*NN + s + m] * segK
#define SEG_CHILD 2   // (b*NN + 2*(s+m)+1)*NH  (512 contiguous = both children)
#define SEG_LVL 3     // (b<<logM + m)*NH
#define SEG_PARENT 4  // (b*(M/2) + m/2)*NH

typedef unsigned short u16;
typedef __attribute__((ext_vector_type(4))) float f32x4;
typedef __attribute__((ext_vector_type(8))) short bf16x8;
typedef __attribute__((ext_vector_type(8))) unsigned short us8;

__device__ __forceinline__ float sigf(float x){ return 1.0f/(1.0f + expf(-x)); }

__device__ __forceinline__ u16 f2bf(float x){
  unsigned int u = __float_as_uint(x);
  unsigned int r = u + 0x7fffu + ((u >> 16) & 1u);
  return (u16)(r >> 16);
}
__device__ __forceinline__ float bf2f(u16 h){
  return __uint_as_float(((unsigned int)h) << 16);
}
__device__ __forceinline__ void store_split(float v, u16* hi, u16* lo, size_t i){
  u16 h = f2bf(v);
  hi[i] = h;
  lo[i] = f2bf(v - bf2f(h));
}

__device__ __forceinline__ long long seg_row_idx(int mode, const int* ids,
                                                 int b, int m, int s, int logM, int segK){
  switch(mode){
    case SEG_EMB:    return (long long)ids[b*NN + s + m] * segK;
    case SEG_CHILD:  return ((long long)(b*NN + 2*(s+m) + 1)) * NH;
    case SEG_LVL:    return (((long long)b << logM) + m) * (long long)NH;
    case SEG_PARENT: return ((long long)(b*(1<<(logM-1)) + (m>>1))) * NH;
    default:         return -1;
  }
}

// Split-precision bf16 MFMA GEMM.
// A rows are virtual concat of up to 3 segments (hi/lo bf16 planes).
// W is pre-transposed+split: Wt[n][k]. G[lr][n] = A[row] @ W + bias  (fp32 out)
// Tile: 128 rows x 128 cols, BK=64, 256 threads = 4 waves (2x2), wave=64x64.
__global__ __launch_bounds__(256, 2) void gemm_mfma(
    int R, int r0, int Ncols, int logM, int s,
    const int* __restrict__ ids,
    int mode0, const u16* __restrict__ p0h, const u16* __restrict__ p0l, int k0,
    int mode1, const u16* __restrict__ p1h, const u16* __restrict__ p1l, int k1,
    int mode2, const u16* __restrict__ p2h, const u16* __restrict__ p2l, int k2,
    const u16* __restrict__ Wth, const u16* __restrict__ Wtl,
    const float* __restrict__ bias, float* __restrict__ G)
{
  __shared__ u16 As[2][8][128][8];   // plane, k-granule(8 elems), row, elem = 32 KB
  __shared__ u16 Bs[2][8][128][8];   // plane, k-granule, col, elem        = 32 KB
  int tid = threadIdx.x;
  int lane = tid & 63;
  int wave = tid >> 6;
  int wr = wave >> 1, wc = wave & 1;

  // loader role: each thread stages one A row and one B col (one plane) per K-step
  int lrow = tid & 127;
  int lpl  = tid >> 7;

  int lr_l = blockIdx.x*128 + lrow;
  int gr_l = r0 + lr_l;
  int b = gr_l >> logM, m = gr_l & ((1<<logM)-1);
  long long ri0 = -1, ri1 = -1, ri2 = -1;
  if (gr_l < R){
    ri0 = seg_row_idx(mode0, ids, b, m, s, logM, k0);
    ri1 = seg_row_idx(mode1, ids, b, m, s, logM, k1);
    ri2 = seg_row_idx(mode2, ids, b, m, s, logM, k2);
  }
  int kTot = k0 + k1 + k2;
  int cb = blockIdx.y * 128;
  long long wbase = (long long)(cb + lrow) * kTot;
  const u16* wp = lpl ? Wtl : Wth;

  f32x4 acc[4][4];
  #pragma unroll
  for (int i=0;i<4;++i)
    #pragma unroll
    for (int j=0;j<4;++j) acc[i][j] = (f32x4)0.0f;

  const us8 zz = (us8)0;

  for (int kt = 0; kt < kTot; kt += 64){
    const u16* ap; long long ai;
    if (kt < k0){ ap = lpl ? p0l : p0h; ai = ri0 + kt; }
    else if (kt < k0 + k1){ ap = lpl ? p1l : p1h; ai = ri1 + (kt - k0); }
    else { ap = lpl ? p2l : p2h; ai = ri2 + (kt - k0 - k1); }
    bool az = (kt < k0) ? (ri0 < 0) : (kt < k0+k1) ? (ri1 < 0) : (ri2 < 0);

    us8 av[8], bv[8];
    #pragma unroll
    for (int g = 0; g < 8; ++g){
      av[g] = az ? zz : *(const us8*)(ap + ai + g*8);
      bv[g] = *(const us8*)(wp + wbase + kt + g*8);
    }
    __syncthreads();
    #pragma unroll
    for (int g = 0; g < 8; ++g){
      *(us8*)&As[lpl][g][lrow][0] = av[g];
      *(us8*)&Bs[lpl][g][lrow][0] = bv[g];
    }
    __syncthreads();

    #pragma unroll
    for (int kc = 0; kc < 2; ++kc){
      int gb = kc*4 + (lane >> 4);
      bf16x8 ah[4], al[4], bh[4], bl[4];
      #pragma unroll
      for (int i = 0; i < 4; ++i){
        int rr = wr*64 + i*16 + (lane & 15);
        ah[i] = *(const bf16x8*)&As[0][gb][rr][0];
        al[i] = *(const bf16x8*)&As[1][gb][rr][0];
      }
      #pragma unroll
      for (int j = 0; j < 4; ++j){
        int cc = wc*64 + j*16 + (lane & 15);
        bh[j] = *(const bf16x8*)&Bs[0][gb][cc][0];
        bl[j] = *(const bf16x8*)&Bs[1][gb][cc][0];
      }
      #pragma unroll
      for (int i = 0; i < 4; ++i)
        #pragma unroll
        for (int j = 0; j < 4; ++j){
          acc[i][j] = __builtin_amdgcn_mfma_f32_16x16x32_bf16(ah[i], bh[j], acc[i][j], 0,0,0);
          acc[i][j] = __builtin_amdgcn_mfma_f32_16x16x32_bf16(al[i], bh[j], acc[i][j], 0,0,0);
          acc[i][j] = __builtin_amdgcn_mfma_f32_16x16x32_bf16(ah[i], bl[j], acc[i][j], 0,0,0);
        }
    }
  }

  // C/D layout (m89-verified): col = lane&15, row = (lane>>4)*4 + r
  int cb2 = cb + wc*64;
  #pragma unroll
  for (int j = 0; j < 4; ++j){
    int col = cb2 + j*16 + (lane & 15);
    float bv = bias[col];
    #pragma unroll
    for (int i = 0; i < 4; ++i){
      int base = blockIdx.x*128 + wr*64 + i*16 + ((lane >> 4) << 2);
      #pragma unroll
      for (int r = 0; r < 4; ++r){
        int row = base + r;
        if (r0 + row < R) G[(size_t)row*Ncols + col] = acc[i][j][r] + bv;
      }
    }
  }
}

// BU node epilogue: G cols = [i|o|u|f0|f1] (width 1280)
__global__ void epi_bu_node(int R, int r0, int logM, int s,
    const float* __restrict__ G, const float* __restrict__ cce,
    float* __restrict__ c_lvl, u16* __restrict__ hl_hi, u16* __restrict__ hl_lo,
    float* __restrict__ out)
{
  int lr = blockIdx.x, gr = r0 + lr;
  if (gr >= R) return;
  int hh = threadIdx.x;
  const float* g = G + (size_t)lr*1280;
  float iv = sigf(g[hh]);
  float ov = sigf(g[256+hh]);
  float uv = tanhf(g[512+hh]);
  float f0 = sigf(g[768+hh]);
  float f1 = sigf(g[1024+hh]);
  int M = 1<<logM; int b = gr >> logM, m = gr & (M-1);
  int j = s + m;
  float c0 = 0.f, c1 = 0.f;
  if (cce){
    c0 = cce[((size_t)(b*NN + 2*j+1))*NH + hh];
    c1 = cce[((size_t)(b*NN + 2*j+2))*NH + hh];
  }
  float c = iv*uv + f0*c0 + f1*c1;
  float h = ov * tanhf(c);
  c_lvl[(size_t)gr*NH + hh] = c;
  store_split(h, hl_hi, hl_lo, (size_t)gr*NH + hh);
  out[((size_t)(b*NN + j))*OUTW + hh] = h;
}

// TD node epilogue: G cols = [i|o|u|f0|f1|fpar] (width 1536)
__global__ void epi_td_node(int R, int r0, int logM, int s,
    const float* __restrict__ G, const float* __restrict__ cce, const float* __restrict__ pc,
    float* __restrict__ c_lvl, u16* __restrict__ hl_hi, u16* __restrict__ hl_lo,
    float* __restrict__ out)
{
  int lr = blockIdx.x, gr = r0 + lr;
  if (gr >= R) return;
  int hh = threadIdx.x;
  const float* g = G + (size_t)lr*1536;
  float iv = sigf(g[hh]);
  float ov = sigf(g[256+hh]);
  float uv = tanhf(g[512+hh]);
  float f0 = sigf(g[768+hh]);
  float f1 = sigf(g[1024+hh]);
  float fp = sigf(g[1280+hh]);
  int M = 1<<logM; int b = gr >> logM, m = gr & (M-1);
  int j = s + m;
  float c0 = 0.f, c1 = 0.f;
  if (cce){
    c0 = cce[((size_t)(b*NN + 2*j+1))*NH + hh];
    c1 = cce[((size_t)(b*NN + 2*j+2))*NH + hh];
  }
  float pcv = pc[(size_t)gr*NH + hh];
  float c = iv*uv + f0*c0 + f1*c1 + fp*pcv;
  float h = ov * tanhf(c);
  c_lvl[(size_t)gr*NH + hh] = c;
  store_split(h, hl_hi, hl_lo, (size_t)gr*NH + hh);
  out[((size_t)(b*NN + j))*OUTW + 256 + hh] = h;
}

// Edge-LSTM epilogue: G cols = [i|f|g|o] (width 1024)
__global__ void epi_lstm(int R, int r0, int logM, int s,
    const float* __restrict__ G, const float* __restrict__ cprev, int parentMode,
    u16* __restrict__ dh_hi, u16* __restrict__ dh_lo, float* __restrict__ dst_c,
    int dstLevelMode)
{
  int lr = blockIdx.x, gr = r0 + lr;
  if (gr >= R) return;
  int hh = threadIdx.x;
  const float* g = G + (size_t)lr*1024;
  float iv = sigf(g[hh]);
  float fv = sigf(g[256+hh]);
  float gg = tanhf(g[512+hh]);
  float ov = sigf(g[768+hh]);
  int M = 1<<logM; int b = gr >> logM, m = gr & (M-1);
  float cp;
  if (parentMode) cp = cprev[((size_t)(b*(M>>1) + (m>>1)))*NH + hh];
  else            cp = cprev[(size_t)gr*NH + hh];
  float c2 = fv*cp + iv*gg;
  float h2 = ov*tanhf(c2);
  size_t di;
  if (dstLevelMode) di = ((size_t)(b*NN + s + m))*NH + hh;
  else              di = (size_t)gr*NH + hh;
  store_split(h2, dh_hi, dh_lo, di);
  dst_c[di] = c2;
}

// ---- weight packing: transposed (Wt[n][k]) + hi/lo split ----

// BU node: K=768 rows [x|cat], 1280 cols [iou(768)|f0|f1]
__global__ void pack_bu_node_t(const float* __restrict__ Wioux, const float* __restrict__ Wiouh,
                               const float* __restrict__ Wfx, const float* __restrict__ Wfh,
                               const float* __restrict__ bioux, const float* __restrict__ bfx,
                               u16* __restrict__ Wth, u16* __restrict__ Wtl, float* __restrict__ bd)
{
  int tid = blockIdx.x*256 + threadIdx.x;
  if (tid < 768*1280){
    int n = tid / 768, k = tid % 768;
    float v;
    if (n < 768){
      v = (k < 256) ? Wioux[k*768 + n] : Wiouh[(k-256)*768 + n];
    } else {
      int kidx = (n < 1024) ? 0 : 1;
      int nn = n - 768 - kidx*256;
      v = (k < 256) ? Wfx[k*256 + nn] : Wfh[((size_t)kidx*512 + (k-256))*256 + nn];
    }
    u16 h = f2bf(v);
    Wth[tid] = h; Wtl[tid] = f2bf(v - bf2f(h));
  }
  if (tid < 1280) bd[tid] = (tid < 768) ? bioux[tid] : bfx[(tid-768) & 255];
}

// Edge LSTM: K=512 rows [x|h], 1024 cols; bias = bih + bhh
__global__ void pack_edge_t(const float* __restrict__ Wih, const float* __restrict__ Whh,
                            const float* __restrict__ bih, const float* __restrict__ bhh,
                            u16* __restrict__ Wth, u16* __restrict__ Wtl, float* __restrict__ bd)
{
  int tid = blockIdx.x*256 + threadIdx.x;
  if (tid < 512*1024){
    int n = tid / 512, k = tid % 512;
    float v = (k < 256) ? Wih[k*1024 + n] : Whh[(k-256)*1024 + n];
    u16 h = f2bf(v);
    Wth[tid] = h; Wtl[tid] = f2bf(v - bf2f(h));
  }
  if (tid < 1024) bd[tid] = bih[tid] + bhh[tid];
}

// TD node: K=1024 rows [x|cat|ph], 1536 cols [iou(768)|f0|f1|fpar]
__global__ void pack_td_node_t(const float* __restrict__ Wioux, const float* __restrict__ Wiouhc,
                               const float* __restrict__ Wiouhp, const float* __restrict__ Wfx,
                               const float* __restrict__ Wfchild, const float* __restrict__ Wfparent,
                               const float* __restrict__ bioux, const float* __restrict__ bfx,
                               u16* __restrict__ Wth, u16* __restrict__ Wtl, float* __restrict__ bd)
{
  int tid = blockIdx.x*256 + threadIdx.x;
  if (tid < 1024*1536){
    int n = tid / 1024, k = tid % 1024;
    float v;
    if (n < 768){
      v = (k < 256) ? Wioux[k*768 + n]
        : (k < 768) ? Wiouhc[(k-256)*768 + n]
                    : Wiouhp[(k-768)*768 + n];
    } else if (n < 1280){
      int kidx = (n < 1024) ? 0 : 1;
      int nn = n - 768 - kidx*256;
      v = (k < 256) ? Wfx[k*256 + nn]
        : (k < 768) ? Wfchild[((size_t)kidx*768 + k)*256 + nn]
                    : Wfchild[((size_t)kidx*768 + (k-768))*256 + nn];
    } else {
      int nn = n - 1280;
      v = (k < 256) ? Wfx[k*256 + nn]
        : (k < 768) ? Wfparent[(size_t)k*256 + nn]
                    : Wfparent[(size_t)(k-768)*256 + nn];
    }
    u16 h = f2bf(v);
    Wth[tid] = h; Wtl[tid] = f2bf(v - bf2f(h));
  }
  if (tid < 1536) bd[tid] = (tid < 768) ? bioux[tid] : bfx[(tid-768) & 255];
}

// Embedding tables: split into hi/lo planes
__global__ void pack_emb(const float* __restrict__ ne, const float* __restrict__ ee,
                         u16* __restrict__ neh, u16* __restrict__ nel,
                         u16* __restrict__ eeh, u16* __restrict__ eel)
{
  int tid = blockIdx.x*256 + threadIdx.x;
  if (tid < 64*256){
    float v = ne[tid]; u16 h = f2bf(v);
    neh[tid] = h; nel[tid] = f2bf(v - bf2f(h));
  }
  if (tid < 128*256){
    float v = ee[tid]; u16 h = f2bf(v);
    eeh[tid] = h; eel[tid] = f2bf(v - bf2f(h));
  }
}

static inline int imin(int a, int b){ return a < b ? a : b; }

extern "C" void kernel_launch(void* const* d_in, const int* in_sizes, int n_in,
                              void* d_out, int out_size, void* d_ws, size_t ws_size,
                              hipStream_t stream)
{
  const float* node_emb  = (const float*)d_in[0];
  const float* edge_emb  = (const float*)d_in[1];
  const float* bu_Wioux  = (const float*)d_in[2];
  const float* bu_bioux  = (const float*)d_in[3];
  const float* bu_Wfx    = (const float*)d_in[4];
  const float* bu_bfx    = (const float*)d_in[5];
  const float* bu_Wiouh  = (const float*)d_in[6];
  const float* bu_Wfh    = (const float*)d_in[7];
  const float* bu_eWih   = (const float*)d_in[8];
  const float* bu_eWhh   = (const float*)d_in[9];
  const float* bu_ebih   = (const float*)d_in[10];
  const float* bu_ebhh   = (const float*)d_in[11];
  const float* td_Wioux  = (const float*)d_in[12];
  const float* td_bioux  = (const float*)d_in[13];
  const float* td_Wfx    = (const float*)d_in[14];
  const float* td_bfx    = (const float*)d_in[15];
  const float* td_Wiouhc = (const float*)d_in[16];
  const float* td_Wiouhp = (const float*)d_in[17];
  const float* td_Wfchild= (const float*)d_in[18];
  const float* td_Wfparent=(const float*)d_in[19];
  const float* td_eWih   = (const float*)d_in[20];
  const float* td_eWhh   = (const float*)d_in[21];
  const float* td_ebih   = (const float*)d_in[22];
  const float* td_ebhh   = (const float*)d_in[23];
  const int* node_ids    = (const int*)d_in[24];
  const int* edge_ids    = (const int*)d_in[25];
  float* out = (float*)d_out;

  // ---- workspace layout: fp32 region, then u16 region, then G ----
  float* fw = (float*)d_ws;
  size_t fo = 0;
  float* bbun = fw + fo; fo += 1280;
  float* bbue = fw + fo; fo += 1024;
  float* btdn = fw + fo; fo += 1536;
  float* btde = fw + fo; fo += 1024;
  float* ce_all = fw + fo; fo += (size_t)NB*NN*NH;
  float* c_lvl  = fw + fo; fo += (size_t)NB*2048*NH;
  float* pc     = fw + fo; fo += (size_t)NB*2048*NH;

  u16* uw = (u16*)(fw + fo);
  size_t uo = 0;
  u16* Wbunh = uw + uo; uo += (size_t)768*1280;
  u16* Wbunl = uw + uo; uo += (size_t)768*1280;
  u16* Wbueh = uw + uo; uo += (size_t)512*1024;
  u16* Wbuel = uw + uo; uo += (size_t)512*1024;
  u16* Wtdnh = uw + uo; uo += (size_t)1024*1536;
  u16* Wtdnl = uw + uo; uo += (size_t)1024*1536;
  u16* Wtdeh = uw + uo; uo += (size_t)512*1024;
  u16* Wtdel = uw + uo; uo += (size_t)512*1024;
  u16* neh = uw + uo; uo += (size_t)64*256;
  u16* nel = uw + uo; uo += (size_t)64*256;
  u16* eeh = uw + uo; uo += (size_t)128*256;
  u16* eel = uw + uo; uo += (size_t)128*256;
  u16* he_hi = uw + uo; uo += (size_t)NB*NN*NH;
  u16* he_lo = uw + uo; uo += (size_t)NB*NN*NH;
  u16* hl_hi = uw + uo; uo += (size_t)NB*2048*NH;
  u16* hl_lo = uw + uo; uo += (size_t)NB*2048*NH;
  u16* ph_hi = uw + uo; uo += (size_t)NB*2048*NH;
  u16* ph_lo = uw + uo; uo += (size_t)NB*2048*NH;

  size_t usedBytes = (fo*sizeof(float) + uo*sizeof(u16) + 15) & ~(size_t)15;
  float* G = (float*)((char*)d_ws + usedBytes);

  int CHUNK = 128;
  if (ws_size > usedBytes){
    size_t remF = (ws_size - usedBytes) / 4;
    size_t c = (remF / 1536) & ~(size_t)127;
    if (c > 8192) c = 8192;
    if (c >= 128) CHUNK = (int)c;
  }

  // ---- pack ----
  pack_bu_node_t<<<(768*1280+255)/256, 256, 0, stream>>>(bu_Wioux, bu_Wiouh, bu_Wfx, bu_Wfh,
      bu_bioux, bu_bfx, Wbunh, Wbunl, bbun);
  pack_edge_t<<<(512*1024+255)/256, 256, 0, stream>>>(bu_eWih, bu_eWhh, bu_ebih, bu_ebhh,
      Wbueh, Wbuel, bbue);
  pack_td_node_t<<<(1024*1536+255)/256, 256, 0, stream>>>(td_Wioux, td_Wiouhc, td_Wiouhp, td_Wfx,
      td_Wfchild, td_Wfparent, td_bioux, td_bfx, Wtdnh, Wtdnl, btdn);
  pack_edge_t<<<(512*1024+255)/256, 256, 0, stream>>>(td_eWih, td_eWhh, td_ebih, td_ebhh,
      Wtdeh, Wtdel, btde);
  pack_emb<<<(128*256+255)/256, 256, 0, stream>>>(node_emb, edge_emb, neh, nel, eeh, eel);

  // ---------- bottom-up ----------
  for (int l = NLV-1; l >= 0; --l){
    int M = 1<<l, s = M-1, R = NB*M;
    bool leaf = (l == NLV-1);
    for (int r0 = 0; r0 < R; r0 += CHUNK){
      int cr = imin(CHUNK, R - r0);
      dim3 g1((cr+127)/128, 1280/128);
      gemm_mfma<<<g1, 256, 0, stream>>>(R, r0, 1280, l, s, node_ids,
          SEG_EMB, neh, nel, 256,
          leaf ? SEG_ZERO : SEG_CHILD, leaf ? nullptr : he_hi, leaf ? nullptr : he_lo, 512,
          SEG_ZERO, nullptr, nullptr, 0,
          Wbunh, Wbunl, bbun, G);
      epi_bu_node<<<cr, 256, 0, stream>>>(R, r0, l, s, G, leaf ? nullptr : ce_all,
          c_lvl, hl_hi, hl_lo, out);
    }
    for (int r0 = 0; r0 < R; r0 += CHUNK){
      int cr = imin(CHUNK, R - r0);
      dim3 g2((cr+127)/128, 1024/128);
      gemm_mfma<<<g2, 256, 0, stream>>>(R, r0, 1024, l, s, edge_ids,
          SEG_EMB, eeh, eel, 256,
          SEG_LVL, hl_hi, hl_lo, 256,
          SEG_ZERO, nullptr, nullptr, 0,
          Wbueh, Wbuel, bbue, G);
      epi_lstm<<<cr, 256, 0, stream>>>(R, r0, l, s, G, c_lvl, 0, he_hi, he_lo, ce_all, 1);
    }
  }

  // ---------- top-down ----------
  hipMemsetAsync(ph_hi, 0, (size_t)NB*NH*sizeof(u16), stream);
  hipMemsetAsync(ph_lo, 0, (size_t)NB*NH*sizeof(u16), stream);
  hipMemsetAsync(pc, 0, (size_t)NB*NH*sizeof(float), stream);
  for (int l = 0; l < NLV; ++l){
    int M = 1<<l, s = M-1, R = NB*M;
    bool leaf = (l == NLV-1);
    for (int r0 = 0; r0 < R; r0 += CHUNK){
      int cr = imin(CHUNK, R - r0);
      dim3 g1((cr+127)/128, 1536/128);
      gemm_mfma<<<g1, 256, 0, stream>>>(R, r0, 1536, l, s, node_ids,
          SEG_EMB, neh, nel, 256,
          leaf ? SEG_ZERO : SEG_CHILD, leaf ? nullptr : he_hi, leaf ? nullptr : he_lo, 512,
          SEG_LVL, ph_hi, ph_lo, 256,
          Wtdnh, Wtdnl, btdn, G);
      epi_td_node<<<cr, 256, 0, stream>>>(R, r0, l, s, G, leaf ? nullptr : ce_all, pc,
          c_lvl, hl_hi, hl_lo, out);
    }
    if (!leaf){
      int M2 = 2*M, s2 = 2*M-1, R2 = NB*M2;
      for (int r0 = 0; r0 < R2; r0 += CHUNK){
        int cr = imin(CHUNK, R2 - r0);
        dim3 g2((cr+127)/128, 1024/128);
        gemm_mfma<<<g2, 256, 0, stream>>>(R2, r0, 1024, l+1, s2, edge_ids,
            SEG_EMB, eeh, eel, 256,
            SEG_PARENT, hl_hi, hl_lo, 256,
            SEG_ZERO, nullptr, nullptr, 0,
            Wtdeh, Wtdel, btde, G);
        epi_lstm<<<cr, 256, 0, stream>>>(R2, r0, l+1, s2, G, c_lvl, 1, ph_hi, ph_lo, pc, 0);
      }
    }
  }
}

// Round 3
// 2177.566 us; speedup vs baseline: 4.2628x; 2.3142x over previous
//
#include <hip/hip_runtime.h>
#include <math.h>

#define NB 16       // batch
#define NH 256      // hidden dim
#define NLV 12      // levels
#define NN 4095     // nodes
#define OUTW 512    // output last-dim (2H)

#define SEG_EMB 1
#define SEG_CHILD 2
#define SEG_LVL 3
#define SEG_PARENT 4

typedef unsigned short u16;
typedef __attribute__((ext_vector_type(4))) float f32x4;
typedef __attribute__((ext_vector_type(8))) short bf16x8;

__device__ __forceinline__ float sigf(float x){ return 1.0f/(1.0f + expf(-x)); }

__device__ __forceinline__ u16 f2bf(float x){
  unsigned int u = __float_as_uint(x);
  return (u16)((u + 0x7fffu + ((u >> 16) & 1u)) >> 16);
}
__device__ __forceinline__ float bf2f(u16 h){
  return __uint_as_float(((unsigned int)h) << 16);
}

// async global->LDS, 16B per lane; LDS dest = wave-uniform base + lane*16
__device__ __forceinline__ void gload16(const void* g, void* l){
  __builtin_amdgcn_global_load_lds(
      (const __attribute__((address_space(1))) unsigned int*)g,
      (__attribute__((address_space(3))) unsigned int*)l, 16, 0, 0);
}

// -------------------------------------------------------------------------
// MFMA GEMM: G[lr][n] = A_row(gr) @ W(:,cb..cb+128) + bias
// A = virtual concat of up to 3 bf16 segments (1 plane).
// W = pre-transposed 2-plane bf16: Wt[n][k], k-stride = wstride.
// Tile: 128 rows x 128 cols, BK=64, 256 thr = 4 waves (2x2), wave = 64x64.
// Staging: global_load_lds w=16, linear LDS dest, pre-swizzled global src;
// reads XOR-swizzled (T2): LDS[r][c16] holds granule (c16 ^ (r&7)).
// -------------------------------------------------------------------------
__global__ __launch_bounds__(256, 3) void gemm_mfma(
    int R, int r0, int Ncols, int logM, int s,
    const int* __restrict__ ids,
    int mode0, const u16* __restrict__ p0, int k0,
    int mode1, const u16* __restrict__ p1, int k1,
    int mode2, const u16* __restrict__ p2, int k2,
    const u16* __restrict__ Wth, const u16* __restrict__ Wtl, int wstride,
    const float* __restrict__ bias, float* __restrict__ G)
{
  __shared__ u16 As[128][64];   // 16 KB
  __shared__ u16 Bh[128][64];   // 16 KB
  __shared__ u16 Bl[128][64];   // 16 KB
  int tid = threadIdx.x, lane = tid & 63, w = tid >> 6;
  int wr = w >> 1, wc = w & 1;
  int swz = ((lane & 7) ^ (lane >> 3)) * 8;   // pre-swizzled k-elem offset in 64-tile
  int cb = blockIdx.y * 128;
  if (!p1) p1 = p0;
  if (!p2) p2 = p0;
  int M = 1 << logM;

  // loader precompute: call j stages rows/cols [j*32 + w*8, +8)
  const u16* pa0[4]; const u16* pa1[4]; const u16* pa2[4];
  const u16* pbh[4]; const u16* pbl[4];
  #pragma unroll
  for (int j = 0; j < 4; ++j){
    int lrow = j*32 + w*8 + (lane >> 3);
    int gr = r0 + blockIdx.x*128 + lrow;
    if (gr > R-1) gr = R-1;                 // clamp OOB rows (stores guarded)
    int b = gr >> logM, m = gr & (M-1);
    long long e0 = (long long)ids[b*NN + s + m] * 256;
    long long e1 = (mode1 == SEG_CHILD) ? ((long long)(b*NN + 2*(s+m) + 1))*NH
                 : (mode1 == SEG_LVL)   ? (((long long)b << logM) + m)*(long long)NH
                 :                        ((long long)(b*(M>>1) + (m>>1)))*NH;
    long long e2 = ((long long)(b*NN + 2*(s+m) + 1))*NH;  // only CHILD ever used as seg2
    pa0[j] = p0 + e0 + swz;
    pa1[j] = p1 + e1 + swz;
    pa2[j] = p2 + e2 + swz;
    long long wb = (long long)(cb + lrow) * wstride + swz;
    pbh[j] = Wth + wb;
    pbl[j] = Wtl + wb;
  }
  int kTot = k0 + k1 + k2;

  f32x4 acc[4][4];
  #pragma unroll
  for (int i = 0; i < 4; ++i)
    #pragma unroll
    for (int j = 0; j < 4; ++j) acc[i][j] = (f32x4)0.0f;

  for (int kt = 0; kt < kTot; kt += 64){
    __syncthreads();                          // LDS free (all waves done reading)
    #pragma unroll
    for (int j = 0; j < 4; ++j){
      const u16* ga;
      if (kt < k0)            ga = pa0[j] + kt;
      else if (kt < k0 + k1)  ga = pa1[j] + (kt - k0);
      else                    ga = pa2[j] + (kt - k0 - k1);
      gload16(ga,            &As[j*32 + w*8][0]);
      gload16(pbh[j] + kt,   &Bh[j*32 + w*8][0]);
      gload16(pbl[j] + kt,   &Bl[j*32 + w*8][0]);
    }
    __syncthreads();                          // loads landed (vmcnt drained)

    #pragma unroll
    for (int kc = 0; kc < 2; ++kc){
      int g2 = ((kc*4 + (lane >> 4)) ^ (lane & 7)) * 8;
      bf16x8 a[4], bhf[4], blf[4];
      #pragma unroll
      for (int i = 0; i < 4; ++i)
        a[i] = *(const bf16x8*)&As[wr*64 + i*16 + (lane & 15)][g2];
      #pragma unroll
      for (int j = 0; j < 4; ++j){
        int cc = wc*64 + j*16 + (lane & 15);
        bhf[j] = *(const bf16x8*)&Bh[cc][g2];
        blf[j] = *(const bf16x8*)&Bl[cc][g2];
      }
      #pragma unroll
      for (int i = 0; i < 4; ++i)
        #pragma unroll
        for (int j = 0; j < 4; ++j){
          acc[i][j] = __builtin_amdgcn_mfma_f32_16x16x32_bf16(a[i], bhf[j], acc[i][j], 0,0,0);
          acc[i][j] = __builtin_amdgcn_mfma_f32_16x16x32_bf16(a[i], blf[j], acc[i][j], 0,0,0);
        }
    }
  }

  // C/D layout: col = lane&15, row = (lane>>4)*4 + r  (m89-verified, R2-passed)
  #pragma unroll
  for (int j = 0; j < 4; ++j){
    int col = cb + wc*64 + j*16 + (lane & 15);
    float bv = bias[col];
    #pragma unroll
    for (int i = 0; i < 4; ++i){
      int base = blockIdx.x*128 + wr*64 + i*16 + ((lane >> 4) << 2);
      #pragma unroll
      for (int r = 0; r < 4; ++r){
        int row = base + r;
        if (r0 + row < R) G[(size_t)row*Ncols + col] = acc[i][j][r] + bv;
      }
    }
  }
}

// ---- epilogues (c-path fp32; h stored bf16 for GEMM reuse, fp32 to out) ----

// BU node: non-leaf gw=1280 [i|o|u|f0|f1]; leaf gw=768 [i|o|u]
__global__ void epi_bu_node(int R, int r0, int logM, int s, int gw,
    const float* __restrict__ G, const float* __restrict__ cce,
    float* __restrict__ c_lvl, u16* __restrict__ hl_b, float* __restrict__ out)
{
  int lr = blockIdx.x, gr = r0 + lr;
  if (gr >= R) return;
  int hh = threadIdx.x;
  const float* g = G + (size_t)lr*gw;
  float iv = sigf(g[hh]);
  float ov = sigf(g[256+hh]);
  float uv = tanhf(g[512+hh]);
  int M = 1<<logM; int b = gr >> logM, m = gr & (M-1);
  int j = s + m;
  float c = iv*uv;
  if (cce){
    float f0 = sigf(g[768+hh]);
    float f1 = sigf(g[1024+hh]);
    c += f0*cce[((size_t)(b*NN + 2*j+1))*NH + hh] + f1*cce[((size_t)(b*NN + 2*j+2))*NH + hh];
  }
  float h = ov * tanhf(c);
  c_lvl[(size_t)gr*NH + hh] = c;
  hl_b[(size_t)gr*NH + hh] = f2bf(h);
  out[((size_t)(b*NN + j))*OUTW + hh] = h;
}

// TD node: non-leaf gw=1536 [i|o|u|fp|f0|f1]; leaf gw=1024 [i|o|u|fp]
__global__ void epi_td_node(int R, int r0, int logM, int s, int gw,
    const float* __restrict__ G, const float* __restrict__ cce, const float* __restrict__ pc,
    float* __restrict__ c_lvl, u16* __restrict__ hl_b, float* __restrict__ out)
{
  int lr = blockIdx.x, gr = r0 + lr;
  if (gr >= R) return;
  int hh = threadIdx.x;
  const float* g = G + (size_t)lr*gw;
  float iv = sigf(g[hh]);
  float ov = sigf(g[256+hh]);
  float uv = tanhf(g[512+hh]);
  float fp = sigf(g[768+hh]);
  int M = 1<<logM; int b = gr >> logM, m = gr & (M-1);
  int j = s + m;
  float c = iv*uv + fp*pc[(size_t)gr*NH + hh];
  if (cce){
    float f0 = sigf(g[1024+hh]);
    float f1 = sigf(g[1280+hh]);
    c += f0*cce[((size_t)(b*NN + 2*j+1))*NH + hh] + f1*cce[((size_t)(b*NN + 2*j+2))*NH + hh];
  }
  float h = ov * tanhf(c);
  c_lvl[(size_t)gr*NH + hh] = c;
  hl_b[(size_t)gr*NH + hh] = f2bf(h);
  out[((size_t)(b*NN + j))*OUTW + 256 + hh] = h;
}

// Edge LSTM: gw=1024 [i|f|g|o]
__global__ void epi_lstm(int R, int r0, int logM, int s,
    const float* __restrict__ G, const float* __restrict__ cprev, int parentMode,
    u16* __restrict__ dh_b, float* __restrict__ dst_c, int dstLevelMode)
{
  int lr = blockIdx.x, gr = r0 + lr;
  if (gr >= R) return;
  int hh = threadIdx.x;
  const float* g = G + (size_t)lr*1024;
  float iv = sigf(g[hh]);
  float fv = sigf(g[256+hh]);
  float gg = tanhf(g[512+hh]);
  float ov = sigf(g[768+hh]);
  int M = 1<<logM; int b = gr >> logM, m = gr & (M-1);
  float cp;
  if (parentMode) cp = cprev[((size_t)(b*(M>>1) + (m>>1)))*NH + hh];
  else            cp = cprev[(size_t)gr*NH + hh];
  float c2 = fv*cp + iv*gg;
  float h2 = ov*tanhf(c2);
  size_t di;
  if (dstLevelMode) di = ((size_t)(b*NN + s + m))*NH + hh;
  else              di = (size_t)gr*NH + hh;
  dh_b[di] = f2bf(h2); dst_c[di] = c2;
}

// ---- weight packing: Wt[n][k], 2-plane hi/lo ----

// BU node: rows [x(256)|cat(512)] k-stride 768; cols [iou(768)|f0|f1]
__global__ void pack_bu_node_t(const float* __restrict__ Wioux, const float* __restrict__ Wiouh,
                               const float* __restrict__ Wfx, const float* __restrict__ Wfh,
                               const float* __restrict__ bioux, const float* __restrict__ bfx,
                               u16* __restrict__ Wth, u16* __restrict__ Wtl, float* __restrict__ bd)
{
  int tid = blockIdx.x*256 + threadIdx.x;
  if (tid < 768*1280){
    int n = tid / 768, k = tid % 768;
    float v;
    if (n < 768){
      v = (k < 256) ? Wioux[k*768 + n] : Wiouh[(k-256)*768 + n];
    } else {
      int kidx = (n < 1024) ? 0 : 1;
      int nn = n - 768 - kidx*256;
      v = (k < 256) ? Wfx[k*256 + nn] : Wfh[((size_t)kidx*512 + (k-256))*256 + nn];
    }
    u16 h = f2bf(v);
    Wth[tid] = h; Wtl[tid] = f2bf(v - bf2f(h));
  }
  if (tid < 1280) bd[tid] = (tid < 768) ? bioux[tid] : bfx[(tid-768) & 255];
}

// Edge: rows [x(256)|h(256)] k-stride 512; cols [i|f|g|o]; bias = bih+bhh
__global__ void pack_edge_t(const float* __restrict__ Wih, const float* __restrict__ Whh,
                            const float* __restrict__ bih, const float* __restrict__ bhh,
                            u16* __restrict__ Wth, u16* __restrict__ Wtl, float* __restrict__ bd)
{
  int tid = blockIdx.x*256 + threadIdx.x;
  if (tid < 512*1024){
    int n = tid / 512, k = tid % 512;
    float v = (k < 256) ? Wih[k*1024 + n] : Whh[(k-256)*1024 + n];
    u16 h = f2bf(v);
    Wth[tid] = h; Wtl[tid] = f2bf(v - bf2f(h));
  }
  if (tid < 1024) bd[tid] = bih[tid] + bhh[tid];
}

// TD node: rows REORDERED [x(256)|ph(256)|cat(512)] k-stride 1024;
// cols REORDERED [iou(768)|fpar(256)|f0(256)|f1(256)]
// pcat = [ph|cat] -> pcat row = k-256 for k in [256,1024)
__global__ void pack_td_node_t(const float* __restrict__ Wioux, const float* __restrict__ Wiouhc,
                               const float* __restrict__ Wiouhp, const float* __restrict__ Wfx,
                               const float* __restrict__ Wfchild, const float* __restrict__ Wfparent,
                               const float* __restrict__ bioux, const float* __restrict__ bfx,
                               u16* __restrict__ Wth, u16* __restrict__ Wtl, float* __restrict__ bd)
{
  int tid = blockIdx.x*256 + threadIdx.x;
  if (tid < 1024*1536){
    int n = tid / 1024, k = tid % 1024;
    float v;
    if (n < 768){
      v = (k < 256) ? Wioux[k*768 + n]
        : (k < 512) ? Wiouhp[(k-256)*768 + n]
                    : Wiouhc[(k-512)*768 + n];
    } else if (n < 1024){
      int nn = n - 768;   // fpar
      v = (k < 256) ? Wfx[k*256 + nn] : Wfparent[(size_t)(k-256)*256 + nn];
    } else {
      int kidx = (n < 1280) ? 0 : 1;
      int nn = n - 1024 - kidx*256;
      v = (k < 256) ? Wfx[k*256 + nn]
                    : Wfchild[((size_t)kidx*768 + (k-256))*256 + nn];
    }
    u16 h = f2bf(v);
    Wth[tid] = h; Wtl[tid] = f2bf(v - bf2f(h));
  }
  if (tid < 1536) bd[tid] = (tid < 768) ? bioux[tid] : bfx[(tid-768) & 255];
}

// Embeddings: single-plane bf16
__global__ void pack_emb(const float* __restrict__ ne, const float* __restrict__ ee,
                         u16* __restrict__ neb, u16* __restrict__ eeb)
{
  int tid = blockIdx.x*256 + threadIdx.x;
  if (tid < 64*256)  neb[tid] = f2bf(ne[tid]);
  if (tid < 128*256) eeb[tid] = f2bf(ee[tid]);
}

static inline int imin(int a, int b){ return a < b ? a : b; }

extern "C" void kernel_launch(void* const* d_in, const int* in_sizes, int n_in,
                              void* d_out, int out_size, void* d_ws, size_t ws_size,
                              hipStream_t stream)
{
  const float* node_emb  = (const float*)d_in[0];
  const float* edge_emb  = (const float*)d_in[1];
  const float* bu_Wioux  = (const float*)d_in[2];
  const float* bu_bioux  = (const float*)d_in[3];
  const float* bu_Wfx    = (const float*)d_in[4];
  const float* bu_bfx    = (const float*)d_in[5];
  const float* bu_Wiouh  = (const float*)d_in[6];
  const float* bu_Wfh    = (const float*)d_in[7];
  const float* bu_eWih   = (const float*)d_in[8];
  const float* bu_eWhh   = (const float*)d_in[9];
  const float* bu_ebih   = (const float*)d_in[10];
  const float* bu_ebhh   = (const float*)d_in[11];
  const float* td_Wioux  = (const float*)d_in[12];
  const float* td_bioux  = (const float*)d_in[13];
  const float* td_Wfx    = (const float*)d_in[14];
  const float* td_bfx    = (const float*)d_in[15];
  const float* td_Wiouhc = (const float*)d_in[16];
  const float* td_Wiouhp = (const float*)d_in[17];
  const float* td_Wfchild= (const float*)d_in[18];
  const float* td_Wfparent=(const float*)d_in[19];
  const float* td_eWih   = (const float*)d_in[20];
  const float* td_eWhh   = (const float*)d_in[21];
  const float* td_ebih   = (const float*)d_in[22];
  const float* td_ebhh   = (const float*)d_in[23];
  const int* node_ids    = (const int*)d_in[24];
  const int* edge_ids    = (const int*)d_in[25];
  float* out = (float*)d_out;

  // ---- workspace ----
  float* fw = (float*)d_ws;
  size_t fo = 0;
  float* bbun = fw + fo; fo += 1280;
  float* bbue = fw + fo; fo += 1024;
  float* btdn = fw + fo; fo += 1536;
  float* btde = fw + fo; fo += 1024;
  float* ce_all = fw + fo; fo += (size_t)NB*NN*NH;
  float* c_lvl  = fw + fo; fo += (size_t)NB*2048*NH;
  float* pc     = fw + fo; fo += (size_t)NB*2048*NH;

  u16* uw = (u16*)(fw + fo);
  size_t uo = 0;
  u16* Wbunh = uw + uo; uo += (size_t)768*1280;
  u16* Wbunl = uw + uo; uo += (size_t)768*1280;
  u16* Wbueh = uw + uo; uo += (size_t)512*1024;
  u16* Wbuel = uw + uo; uo += (size_t)512*1024;
  u16* Wtdnh = uw + uo; uo += (size_t)1024*1536;
  u16* Wtdnl = uw + uo; uo += (size_t)1024*1536;
  u16* Wtdeh = uw + uo; uo += (size_t)512*1024;
  u16* Wtdel = uw + uo; uo += (size_t)512*1024;
  u16* neb = uw + uo; uo += (size_t)64*256;
  u16* eeb = uw + uo; uo += (size_t)128*256;
  u16* he_b = uw + uo; uo += (size_t)NB*NN*NH;
  u16* hl_b = uw + uo; uo += (size_t)NB*2048*NH;
  u16* ph_b = uw + uo; uo += (size_t)NB*2048*NH;

  size_t usedBytes = (fo*sizeof(float) + uo*sizeof(u16) + 255) & ~(size_t)255;
  float* G = (float*)((char*)d_ws + usedBytes);

  int CHUNK = 128;
  if (ws_size > usedBytes){
    size_t remF = (ws_size - usedBytes) / 4;
    size_t c = (remF / 1536) & ~(size_t)127;
    if (c > 8192) c = 8192;
    if (c >= 128) CHUNK = (int)c;
  }

  // ---- pack ----
  pack_bu_node_t<<<(768*1280+255)/256, 256, 0, stream>>>(bu_Wioux, bu_Wiouh, bu_Wfx, bu_Wfh,
      bu_bioux, bu_bfx, Wbunh, Wbunl, bbun);
  pack_edge_t<<<(512*1024+255)/256, 256, 0, stream>>>(bu_eWih, bu_eWhh, bu_ebih, bu_ebhh,
      Wbueh, Wbuel, bbue);
  pack_td_node_t<<<(1024*1536+255)/256, 256, 0, stream>>>(td_Wioux, td_Wiouhc, td_Wiouhp, td_Wfx,
      td_Wfchild, td_Wfparent, td_bioux, td_bfx, Wtdnh, Wtdnl, btdn);
  pack_edge_t<<<(512*1024+255)/256, 256, 0, stream>>>(td_eWih, td_eWhh, td_ebih, td_ebhh,
      Wtdeh, Wtdel, btde);
  pack_emb<<<(128*256+255)/256, 256, 0, stream>>>(node_emb, edge_emb, neb, eeb);

  // ---------- bottom-up ----------
  for (int l = NLV-1; l >= 0; --l){
    int M = 1<<l, s = M-1, R = NB*M;
    bool leaf = (l == NLV-1);
    int gw = leaf ? 768 : 1280;
    for (int r0 = 0; r0 < R; r0 += CHUNK){
      int cr = imin(CHUNK, R - r0);
      dim3 g1((cr+127)/128, gw/128);
      gemm_mfma<<<g1, 256, 0, stream>>>(R, r0, gw, l, s, node_ids,
          SEG_EMB, neb, 256,
          SEG_CHILD, leaf ? nullptr : he_b, leaf ? 0 : 512,
          SEG_CHILD, nullptr, 0,
          Wbunh, Wbunl, 768, bbun, G);
      epi_bu_node<<<cr, 256, 0, stream>>>(R, r0, l, s, gw, G,
          leaf ? nullptr : ce_all, c_lvl, hl_b, out);
    }
    for (int r0 = 0; r0 < R; r0 += CHUNK){
      int cr = imin(CHUNK, R - r0);
      dim3 g2((cr+127)/128, 1024/128);
      gemm_mfma<<<g2, 256, 0, stream>>>(R, r0, 1024, l, s, edge_ids,
          SEG_EMB, eeb, 256,
          SEG_LVL, hl_b, 256,
          SEG_CHILD, nullptr, 0,
          Wbueh, Wbuel, 512, bbue, G);
      epi_lstm<<<cr, 256, 0, stream>>>(R, r0, l, s, G, c_lvl, 0, he_b, ce_all, 1);
    }
  }

  // ---------- top-down ----------
  hipMemsetAsync(ph_b, 0, (size_t)NB*NH*sizeof(u16), stream);
  hipMemsetAsync(pc, 0, (size_t)NB*NH*sizeof(float), stream);
  for (int l = 0; l < NLV; ++l){
    int M = 1<<l, s = M-1, R = NB*M;
    bool leaf = (l == NLV-1);
    int gw = leaf ? 1024 : 1536;
    for (int r0 = 0; r0 < R; r0 += CHUNK){
      int cr = imin(CHUNK, R - r0);
      dim3 g1((cr+127)/128, gw/128);
      gemm_mfma<<<g1, 256, 0, stream>>>(R, r0, gw, l, s, node_ids,
          SEG_EMB, neb, 256,
          SEG_LVL, ph_b, 256,
          SEG_CHILD, leaf ? nullptr : he_b, leaf ? 0 : 512,
          Wtdnh, Wtdnl, 1024, btdn, G);
      epi_td_node<<<cr, 256, 0, stream>>>(R, r0, l, s, gw, G,
          leaf ? nullptr : ce_all, pc, c_lvl, hl_b, out);
    }
    if (!leaf){
      int M2 = 2*M, s2 = 2*M-1, R2 = NB*M2;
      for (int r0 = 0; r0 < R2; r0 += CHUNK){
        int cr = imin(CHUNK, R2 - r0);
        dim3 g2((cr+127)/128, 1024/128);
        gemm_mfma<<<g2, 256, 0, stream>>>(R2, r0, 1024, l+1, s2, edge_ids,
            SEG_EMB, eeb, 256,
            SEG_PARENT, hl_b, 256,
            SEG_CHILD, nullptr, 0,
            Wtdeh, Wtdel, 512, btde, G);
        epi_lstm<<<cr, 256, 0, stream>>>(R2, r0, l+1, s2, G, c_lvl, 1, ph_b, pc, 0);
      }
    }
  }
}